// Round 10
// baseline (130.269 us; speedup 1.0000x reference)
//
#include <hip/hip_runtime.h>
#include <math.h>

#define BLOCK 256
#define QPT 8          // queries per thread
#define TILE 512       // max train points staged per iteration
#define TILE2 (TILE / 2)
#define MAX_SEGS 128
#define RSPLIT 4       // seg-parallelism per query in the reduce

typedef float v2f __attribute__((ext_vector_type(2)));

// scores = -0.5*((q-x)*w)^2 ; fold sqrt(0.5*log2(e)) into w so the needed
// function is exp2: e = 2^s with s = -(t*t), t = fma(q, a, nb),
// a = w*K, nb = -x*w*K.
#define KFOLD 0.8493218f  // sqrt(0.5 * log2(e))
#define MAGIC 12582912.0f // 2^23 * 1.5 : RN rounds s into low mantissa bits

// all-VALU packed exp2 (no v_exp_f32, whose issue serializes ~16cyc/wave).
// Range reduce: i = round(s) via magic-number add (exact), f = s - i
// (exact, in [-0.5,0.5]); degree-5 Horner for 2^f (|err|<=2.4e-6);
// scale by 2^i via v_cvt_i32_f32 + v_ldexp_f32 (HW-exact for any i,
// flushes deep-negative i to 0 -> no clamp needed).
__device__ __forceinline__ v2f exp2_pk(v2f s) {
    v2f z = s + (v2f){MAGIC, MAGIC};                 // pk_add (RN)
    v2f fi = z - (v2f){MAGIC, MAGIC};                // = round(s), exact
    v2f f = s - fi;                                  // [-0.5, 0.5], exact
    const float c1 = 0.69314718056f, c2 = 0.24022650696f,
                c3 = 0.05550410866f, c4 = 0.00961812911f,
                c5 = 0.00133335581f;
    v2f p = __builtin_elementwise_fma(f, (v2f){c5, c5}, (v2f){c4, c4});
    p = __builtin_elementwise_fma(f, p, (v2f){c3, c3});
    p = __builtin_elementwise_fma(f, p, (v2f){c2, c2});
    p = __builtin_elementwise_fma(f, p, (v2f){c1, c1});
    p = __builtin_elementwise_fma(f, p, (v2f){1.f, 1.f});
    float e0 = ldexpf(p.x, (int)fi.x);               // v_ldexp_f32
    float e1 = ldexpf(p.y, (int)fi.y);
    return (v2f){e0, e1};
}

__global__ __launch_bounds__(BLOCK, 4) void nw_partial(
    const float* __restrict__ q, const float* __restrict__ xt,
    const float* __restrict__ yt, const float* __restrict__ w,
    float2* __restrict__ partial, int n_q, int n_t, int segs)
{
    // SoA pair layout: ds_read_b128 yields {a0,a1},{nb0,nb1} aligned for
    // v_pk_fma_f32; ds_read_b64 yields {y0,y1} for the packed accumulate.
    __shared__ float4 tileA[TILE2];   // {a_j, a_j+1, nb_j, nb_j+1}
    __shared__ float2 tileY[TILE2];   // {y_j, y_j+1}

    const int seg = blockIdx.x;
    const int tid = threadIdx.x;
    const int qbase = blockIdx.y * (BLOCK * QPT) + tid;

    v2f q2[QPT];       // {q_i, q_i} splat, loop-invariant
    v2f num2[QPT], den2[QPT];
#pragma unroll
    for (int i = 0; i < QPT; ++i) {
        int qi = qbase + i * BLOCK;
        float qv = (qi < n_q) ? q[qi] : 0.f;
        q2[i] = (v2f){qv, qv};
        num2[i] = (v2f){0.f, 0.f};
        den2[i] = (v2f){0.f, 0.f};
    }

    const int seg_len = (n_t + segs - 1) / segs;
    const int s0 = seg * seg_len;
    const int s1 = min(s0 + seg_len, n_t);

    float* tA = (float*)tileA;
    float* tY = (float*)tileY;

    for (int base = s0; base < s1; base += TILE) {
        const int cnt = min(TILE, s1 - base);
        const int cnt2 = (cnt + 1) >> 1;
        __syncthreads();
        for (int l = tid; l < cnt; l += BLOCK) {
            int jj = base + l;
            float a = w[jj] * KFOLD;
            float nb = -xt[jj] * a;
            int p = l >> 1, h = l & 1;
            tA[p * 4 + h] = a;
            tA[p * 4 + 2 + h] = nb;
            tY[p * 2 + h] = yt[jj];
        }
        if (tid == 0 && (cnt & 1)) {   // pad odd tail: s=-10201 -> e = 0
            int p = cnt >> 1;
            tA[p * 4 + 1] = 0.f;
            tA[p * 4 + 3] = 101.0f;
            tY[p * 2 + 1] = 0.f;
        }
        __syncthreads();
#pragma unroll 4
        for (int j2 = 0; j2 < cnt2; ++j2) {
            float4 A = tileA[j2];
            float2 Y = tileY[j2];
            v2f a2 = (v2f){A.x, A.y};
            v2f nb2 = (v2f){A.z, A.w};
            v2f y2 = (v2f){Y.x, Y.y};
#pragma unroll
            for (int i = 0; i < QPT; ++i) {
                v2f t = __builtin_elementwise_fma(q2[i], a2, nb2);
                v2f s = -(t * t);            // v_pk_mul_f32 with neg mod
                v2f e = exp2_pk(s);
                num2[i] = __builtin_elementwise_fma(e, y2, num2[i]);
                den2[i] = den2[i] + e;       // v_pk_add_f32
            }
        }
    }

#pragma unroll
    for (int i = 0; i < QPT; ++i) {
        int qi = qbase + i * BLOCK;
        if (qi < n_q)
            partial[seg * n_q + qi] =
                make_float2(num2[i].x + num2[i].y, den2[i].x + den2[i].y);
    }
}

// Block handles 64 queries; RSPLIT waves split the segs dimension so each
// wave's 64 lanes read 64 consecutive qi -> fully coalesced.
__global__ __launch_bounds__(BLOCK) void nw_reduce(
    const float2* __restrict__ partial, float* __restrict__ out,
    int n_q, int segs)
{
    __shared__ float2 red[RSPLIT][64];
    const int tid = threadIdx.x;
    const int c = tid >> 6;          // 0..3 (seg chunk = wave index)
    const int ql = tid & 63;         // query within block
    const int qi = blockIdx.x * 64 + ql;

    float num = 0.f, den = 0.f;
    if (qi < n_q) {
        for (int s = c; s < segs; s += RSPLIT) {
            float2 p = partial[(size_t)s * n_q + qi];
            num += p.x;
            den += p.y;
        }
    }
    red[c][ql] = make_float2(num, den);
    __syncthreads();
    if (c == 0 && qi < n_q) {
        float2 r1 = red[1][ql], r2 = red[2][ql], r3 = red[3][ql];
        num += r1.x + r2.x + r3.x;
        den += r1.y + r2.y + r3.y;
        out[qi] = num / den;
    }
}

extern "C" void kernel_launch(void* const* d_in, const int* in_sizes, int n_in,
                              void* d_out, int out_size, void* d_ws, size_t ws_size,
                              hipStream_t stream) {
    const float* q  = (const float*)d_in[0];
    const float* xt = (const float*)d_in[1];
    const float* yt = (const float*)d_in[2];
    const float* w  = (const float*)d_in[3];
    const int n_q = in_sizes[0];
    const int n_t = in_sizes[1];

    // split-K segments, clamped so partials fit in the workspace
    int segs = MAX_SEGS;
    size_t need = (size_t)segs * (size_t)n_q * sizeof(float2);
    if (need > ws_size) {
        segs = (int)(ws_size / ((size_t)n_q * sizeof(float2)));
        if (segs < 1) segs = 1;
    }

    float2* partial = (float2*)d_ws;
    dim3 grid(segs, (n_q + BLOCK * QPT - 1) / (BLOCK * QPT));
    nw_partial<<<grid, BLOCK, 0, stream>>>(q, xt, yt, w, partial, n_q, n_t, segs);
    nw_reduce<<<(n_q + 63) / 64, BLOCK, 0, stream>>>(partial, (float*)d_out,
                                                     n_q, segs);
}

// Round 11
// 126.460 us; speedup vs baseline: 1.0301x; 1.0301x over previous
//
#include <hip/hip_runtime.h>

#define BLOCK 256
#define QPT 8          // queries per thread
#define TILE 512       // max train points staged per iteration
#define TILE2 (TILE / 2)
#define MAX_SEGS 128
#define RSPLIT 4       // seg-parallelism per query in the reduce

typedef _Float16 h2 __attribute__((ext_vector_type(2)));
typedef unsigned short w2 __attribute__((ext_vector_type(2)));
typedef unsigned short u16;

// scores = -0.5*((q-x)*w)^2 ; fold sqrt(0.5*log2(e)) into w so the needed
// function is exp2: e = 2^s, s = -(t*t), t = fma(q, a, b), a=w*K, b=-x*w*K.
#define KFOLD 0.8493218f  // sqrt(0.5 * log2(e))

// Packed-f16 exp2 (full-rate v_pk_* ops; v_exp_f32 issue-serializes
// ~16cyc/wave and f32 "packed" ops don't double rate on gfx950).
// s clamped to [-14, 0]; z = s + 1536 (binade [1024,2048), ulp=1) makes
// z-1536 = round(s) exact; f = s - i exact (Sterbenz); deg-3 Horner for
// 2^f; 2^i spliced per-half: bits(1536)=0x6600, low10=0x200, and
// (0x200+i)<<10 mod 2^16 == i<<10, so eb = pb + (zb<<10) via pk ops.
__device__ __forceinline__ h2 exp2_pk16(h2 s) {
    const h2 clampv = {(_Float16)-14.0f, (_Float16)-14.0f};
    const h2 magic = {(_Float16)1536.0f, (_Float16)1536.0f};
    const h2 nmagic = {(_Float16)-1536.0f, (_Float16)-1536.0f};
    s = __builtin_elementwise_max(s, clampv);
    h2 z = s + magic;            // v_pk_add_f16 (RN -> integer in mantissa)
    h2 fi = z + nmagic;          // = round(s), exact
    h2 f = s - fi;               // [-0.5, 0.5], exact
    const h2 c3 = {(_Float16)0.0555041f, (_Float16)0.0555041f};
    const h2 c2 = {(_Float16)0.2402265f, (_Float16)0.2402265f};
    const h2 c1 = {(_Float16)0.6931472f, (_Float16)0.6931472f};
    const h2 c0 = {(_Float16)1.0003f,    (_Float16)1.0003f};
    h2 p = __builtin_elementwise_fma(f, c3, c2);
    p = __builtin_elementwise_fma(f, p, c1);
    p = __builtin_elementwise_fma(f, p, c0);
    w2 zb = __builtin_bit_cast(w2, z);
    w2 i10 = zb << 10;                       // v_pk_lshlrev_b16 (per-half)
    w2 eb = __builtin_bit_cast(w2, p) + i10; // v_pk_add_u16 (per-half wrap)
    return __builtin_bit_cast(h2, eb);
}

__global__ __launch_bounds__(BLOCK, 4) void nw_partial(
    const float* __restrict__ q, const float* __restrict__ xt,
    const float* __restrict__ yt, const float* __restrict__ w,
    float2* __restrict__ partial, int n_q, int n_t, int segs)
{
    // per j2-pair, 16B: u16[8] = {a0,a1, b0,b1, y0,y1, pad,pad} -> one
    // ds_read_b128 delivers h2 a2,b2,y2 ready for pk ops.
    __shared__ u16 tileH[TILE2 * 8];

    const int seg = blockIdx.x;
    const int tid = threadIdx.x;
    const int qbase = blockIdx.y * (BLOCK * QPT) + tid;

    h2 q2[QPT];        // {q_i, q_i} f16 splat, loop-invariant
    float num[QPT], den[QPT];
#pragma unroll
    for (int i = 0; i < QPT; ++i) {
        int qi = qbase + i * BLOCK;
        float qv = (qi < n_q) ? q[qi] : 0.f;
        _Float16 qh = (_Float16)qv;
        q2[i] = (h2){qh, qh};
        num[i] = 0.f;
        den[i] = 0.f;
    }

    const int seg_len = (n_t + segs - 1) / segs;
    const int s0 = seg * seg_len;
    const int s1 = min(s0 + seg_len, n_t);

    const h2 one2 = {(_Float16)1.0f, (_Float16)1.0f};

    for (int base = s0; base < s1; base += TILE) {
        const int cnt = min(TILE, s1 - base);
        const int cnt2 = (cnt + 1) >> 1;
        __syncthreads();
        for (int l = tid; l < cnt; l += BLOCK) {
            int jj = base + l;
            float a = w[jj] * KFOLD;
            float b = -xt[jj] * a;
            int p = l >> 1, h = l & 1;
            tileH[p * 8 + h]     = __builtin_bit_cast(u16, (_Float16)a);
            tileH[p * 8 + 2 + h] = __builtin_bit_cast(u16, (_Float16)b);
            tileH[p * 8 + 4 + h] = __builtin_bit_cast(u16, (_Float16)yt[jj]);
        }
        if (tid == 0 && (cnt & 1)) {  // pad odd tail: t=-14 -> s clamps, y=0
            int p = cnt >> 1;
            tileH[p * 8 + 1] = __builtin_bit_cast(u16, (_Float16)0.0f);
            tileH[p * 8 + 3] = __builtin_bit_cast(u16, (_Float16)-14.0f);
            tileH[p * 8 + 5] = __builtin_bit_cast(u16, (_Float16)0.0f);
        }
        __syncthreads();
        const uint4* tile4 = (const uint4*)tileH;
#pragma unroll 4
        for (int j2 = 0; j2 < cnt2; ++j2) {
            uint4 V = tile4[j2];
            h2 a2 = __builtin_bit_cast(h2, (unsigned int)V.x);
            h2 b2 = __builtin_bit_cast(h2, (unsigned int)V.y);
            h2 y2 = __builtin_bit_cast(h2, (unsigned int)V.z);
#pragma unroll
            for (int i = 0; i < QPT; ++i) {
                h2 t = __builtin_elementwise_fma(q2[i], a2, b2);
                h2 s = -(t * t);             // v_pk_mul_f16 w/ neg mods
                h2 e = exp2_pk16(s);
                num[i] = __builtin_amdgcn_fdot2(e, y2, num[i], false);
                den[i] = __builtin_amdgcn_fdot2(e, one2, den[i], false);
            }
        }
    }

#pragma unroll
    for (int i = 0; i < QPT; ++i) {
        int qi = qbase + i * BLOCK;
        if (qi < n_q) partial[seg * n_q + qi] = make_float2(num[i], den[i]);
    }
}

// Block handles 64 queries; RSPLIT waves split the segs dimension so each
// wave's 64 lanes read 64 consecutive qi -> fully coalesced.
__global__ __launch_bounds__(BLOCK) void nw_reduce(
    const float2* __restrict__ partial, float* __restrict__ out,
    int n_q, int segs)
{
    __shared__ float2 red[RSPLIT][64];
    const int tid = threadIdx.x;
    const int c = tid >> 6;          // 0..3 (seg chunk = wave index)
    const int ql = tid & 63;         // query within block
    const int qi = blockIdx.x * 64 + ql;

    float num = 0.f, den = 0.f;
    if (qi < n_q) {
        for (int s = c; s < segs; s += RSPLIT) {
            float2 p = partial[(size_t)s * n_q + qi];
            num += p.x;
            den += p.y;
        }
    }
    red[c][ql] = make_float2(num, den);
    __syncthreads();
    if (c == 0 && qi < n_q) {
        float2 r1 = red[1][ql], r2 = red[2][ql], r3 = red[3][ql];
        num += r1.x + r2.x + r3.x;
        den += r1.y + r2.y + r3.y;
        out[qi] = num / den;
    }
}

extern "C" void kernel_launch(void* const* d_in, const int* in_sizes, int n_in,
                              void* d_out, int out_size, void* d_ws, size_t ws_size,
                              hipStream_t stream) {
    const float* q  = (const float*)d_in[0];
    const float* xt = (const float*)d_in[1];
    const float* yt = (const float*)d_in[2];
    const float* w  = (const float*)d_in[3];
    const int n_q = in_sizes[0];
    const int n_t = in_sizes[1];

    // split-K segments, clamped so partials fit in the workspace
    int segs = MAX_SEGS;
    size_t need = (size_t)segs * (size_t)n_q * sizeof(float2);
    if (need > ws_size) {
        segs = (int)(ws_size / ((size_t)n_q * sizeof(float2)));
        if (segs < 1) segs = 1;
    }

    float2* partial = (float2*)d_ws;
    dim3 grid(segs, (n_q + BLOCK * QPT - 1) / (BLOCK * QPT));
    nw_partial<<<grid, BLOCK, 0, stream>>>(q, xt, yt, w, partial, n_q, n_t, segs);
    nw_reduce<<<(n_q + 63) / 64, BLOCK, 0, stream>>>(partial, (float*)d_out,
                                                     n_q, segs);
}

// Round 12
// 109.927 us; speedup vs baseline: 1.1850x; 1.1504x over previous
//
#include <hip/hip_runtime.h>
#include <hip/hip_fp16.h>

#define BLOCK 256
#define QPT 8          // queries per thread
#define TILE 512       // max train points staged per iteration
#define TILE2 (TILE / 2)
#define MAX_SEGS 128
#define RSPLIT 4       // seg-parallelism per query in the reduce

typedef _Float16 h2 __attribute__((ext_vector_type(2)));
typedef unsigned short u16;

// scores = -0.5*((q-x)*w)^2 ; fold sqrt(0.5*log2(e)) into w so the needed
// function is exp2: e = 2^s, s = -(t*t), t = fma(q, a, b), a=w*K, b=-x*w*K.
#define KFOLD 0.8493218f  // sqrt(0.5 * log2(e))

__global__ __launch_bounds__(BLOCK, 4) void nw_partial(
    const float* __restrict__ q, const float* __restrict__ xt,
    const float* __restrict__ yt, const float* __restrict__ w,
    float2* __restrict__ partial, int n_q, int n_t, int segs)
{
    // per j2-pair, 16B: u16[8] = {a0,a1, b0,b1, y0,y1, pad,pad} -> one
    // ds_read_b128 delivers h2 a2,b2,y2 ready for pk ops.
    __shared__ u16 tileH[TILE2 * 8];

    const int seg = blockIdx.x;
    const int tid = threadIdx.x;
    const int qbase = blockIdx.y * (BLOCK * QPT) + tid;

    h2 q2[QPT];        // {q_i, q_i} f16 splat, loop-invariant
    float num[QPT], den[QPT];
#pragma unroll
    for (int i = 0; i < QPT; ++i) {
        int qi = qbase + i * BLOCK;
        float qv = (qi < n_q) ? q[qi] : 0.f;
        _Float16 qh = (_Float16)qv;
        q2[i] = (h2){qh, qh};
        num[i] = 0.f;
        den[i] = 0.f;
    }

    const int seg_len = (n_t + segs - 1) / segs;
    const int s0 = seg * seg_len;
    const int s1 = min(s0 + seg_len, n_t);

    const h2 one2 = {(_Float16)1.0f, (_Float16)1.0f};

    for (int base = s0; base < s1; base += TILE) {
        const int cnt = min(TILE, s1 - base);
        const int cnt2 = (cnt + 1) >> 1;
        __syncthreads();
        for (int l = tid; l < cnt; l += BLOCK) {
            int jj = base + l;
            float a = w[jj] * KFOLD;
            float b = -xt[jj] * a;
            int p = l >> 1, h = l & 1;
            tileH[p * 8 + h]     = __builtin_bit_cast(u16, (_Float16)a);
            tileH[p * 8 + 2 + h] = __builtin_bit_cast(u16, (_Float16)b);
            tileH[p * 8 + 4 + h] = __builtin_bit_cast(u16, (_Float16)yt[jj]);
        }
        if (tid == 0 && (cnt & 1)) {  // pad odd tail: t=-240 -> e underflows
            int p = cnt >> 1;         // to 0 in f16, y=0
            tileH[p * 8 + 1] = __builtin_bit_cast(u16, (_Float16)0.0f);
            tileH[p * 8 + 3] = __builtin_bit_cast(u16, (_Float16)-240.0f);
            tileH[p * 8 + 5] = __builtin_bit_cast(u16, (_Float16)0.0f);
        }
        __syncthreads();
        const uint4* tile4 = (const uint4*)tileH;
#pragma unroll 4
        for (int j2 = 0; j2 < cnt2; ++j2) {
            uint4 V = tile4[j2];
            h2 a2 = __builtin_bit_cast(h2, (unsigned int)V.x);
            h2 b2 = __builtin_bit_cast(h2, (unsigned int)V.y);
            h2 y2 = __builtin_bit_cast(h2, (unsigned int)V.z);
#pragma unroll
            for (int i = 0; i < QPT; ++i) {
                h2 t = __builtin_elementwise_fma(q2[i], a2, b2);
                h2 s = -(t * t);             // v_pk_mul_f16 w/ neg mods
                // v_exp_f16 per half: HW exp2, underflow->0 handles far
                // pairs exactly (no clamp needed)
                __half e0 = hexp2(__builtin_bit_cast(__half, (_Float16)s.x));
                __half e1 = hexp2(__builtin_bit_cast(__half, (_Float16)s.y));
                h2 e = (h2){__builtin_bit_cast(_Float16, e0),
                            __builtin_bit_cast(_Float16, e1)};
                num[i] = __builtin_amdgcn_fdot2(e, y2, num[i], false);
                den[i] = __builtin_amdgcn_fdot2(e, one2, den[i], false);
            }
        }
    }

#pragma unroll
    for (int i = 0; i < QPT; ++i) {
        int qi = qbase + i * BLOCK;
        if (qi < n_q) partial[seg * n_q + qi] = make_float2(num[i], den[i]);
    }
}

// Block handles 64 queries; RSPLIT waves split the segs dimension so each
// wave's 64 lanes read 64 consecutive qi -> fully coalesced.
__global__ __launch_bounds__(BLOCK) void nw_reduce(
    const float2* __restrict__ partial, float* __restrict__ out,
    int n_q, int segs)
{
    __shared__ float2 red[RSPLIT][64];
    const int tid = threadIdx.x;
    const int c = tid >> 6;          // 0..3 (seg chunk = wave index)
    const int ql = tid & 63;         // query within block
    const int qi = blockIdx.x * 64 + ql;

    float num = 0.f, den = 0.f;
    if (qi < n_q) {
        for (int s = c; s < segs; s += RSPLIT) {
            float2 p = partial[(size_t)s * n_q + qi];
            num += p.x;
            den += p.y;
        }
    }
    red[c][ql] = make_float2(num, den);
    __syncthreads();
    if (c == 0 && qi < n_q) {
        float2 r1 = red[1][ql], r2 = red[2][ql], r3 = red[3][ql];
        num += r1.x + r2.x + r3.x;
        den += r1.y + r2.y + r3.y;
        out[qi] = num / den;
    }
}

extern "C" void kernel_launch(void* const* d_in, const int* in_sizes, int n_in,
                              void* d_out, int out_size, void* d_ws, size_t ws_size,
                              hipStream_t stream) {
    const float* q  = (const float*)d_in[0];
    const float* xt = (const float*)d_in[1];
    const float* yt = (const float*)d_in[2];
    const float* w  = (const float*)d_in[3];
    const int n_q = in_sizes[0];
    const int n_t = in_sizes[1];

    // split-K segments, clamped so partials fit in the workspace
    int segs = MAX_SEGS;
    size_t need = (size_t)segs * (size_t)n_q * sizeof(float2);
    if (need > ws_size) {
        segs = (int)(ws_size / ((size_t)n_q * sizeof(float2)));
        if (segs < 1) segs = 1;
    }

    float2* partial = (float2*)d_ws;
    dim3 grid(segs, (n_q + BLOCK * QPT - 1) / (BLOCK * QPT));
    nw_partial<<<grid, BLOCK, 0, stream>>>(q, xt, yt, w, partial, n_q, n_t, segs);
    nw_reduce<<<(n_q + 63) / 64, BLOCK, 0, stream>>>(partial, (float*)d_out,
                                                     n_q, segs);
}